// Round 1
// baseline (311.537 us; speedup 1.0000x reference)
//
#include <hip/hip_runtime.h>

// Correlation cost volume, MAX_DISP=4 (81 displacements).
// B=4, C=128, H=128, W=192. out[b,(dy+4)*9+(dx+4),y,x] =
//   (1/C) * sum_c first[b,c,y,x]*second[b,c,y+dy,x+dx], zero-padded.
//
// Decomposition: tile 64x8 pixels, 128 threads (16 thr x 4 px in x, 8 rows).
// Each block handles 3 dy values (27 displacements) -> acc = 27 float4 = 108 VGPRs.
// grid = (3 xtiles, 16 ytiles, 4 B * 3 dy-groups) = 576 blocks.
// first: read directly (each thread's own float4, coalesced; no LDS).
// second: staged in LDS (10 rows x 72 cols per channel), double-buffered,
// depth-2 register prefetch, one barrier per channel.

#define B_    4
#define C_    128
#define H_    128
#define W_    192
#define HW_   (H_ * W_)
#define CHW_  (C_ * HW_)

#define TX    64    // tile width (pixels)
#define TY    8     // tile height
#define SROWS 10    // TY + 2 (3 dy values per group)
#define SCOLS 72    // TX + 8 halo
#define SFLOATS (SROWS * SCOLS)   // 720
#define NCHUNK  (SFLOATS / 4)     // 180 float4 chunks

__global__ __launch_bounds__(128, 2)
void corr_kernel(const float* __restrict__ first,
                 const float* __restrict__ second,
                 float* __restrict__ out)
{
    __shared__ float sS[2][SFLOATS];

    const int t  = threadIdx.x;
    const int tx = t & 15;       // 0..15 (4 px each)
    const int ty = t >> 4;       // 0..7
    const int x0 = blockIdx.x * TX;
    const int y0 = blockIdx.y * TY;
    const int bz = blockIdx.z;   // b*3 + g
    const int b  = bz / 3;
    const int g  = bz - 3 * b;   // dy group: dy in {3g-4, 3g-3, 3g-2}
    const int dy0 = 3 * g - 4;

    const int X = x0 + 4 * tx;   // this thread's first output x
    const int y = y0 + ty;

    const float* fptr = first + (size_t)b * CHW_ + (size_t)y * W_ + X;

    // --- staging chunk assignment (second tile: SROWS x SCOLS, zero-padded) ---
    // chunk k covers LDS floats [4k, 4k+4): row = k/18, col = 4*(k%18).
    const int k0 = t;
    const int r0 = k0 / 18, cc0 = k0 % 18;
    const int grow0 = y0 + dy0 + r0;
    const int gcol0 = x0 - 4 + 4 * cc0;
    const bool v0 = (grow0 >= 0) && (grow0 < H_) && (gcol0 >= 0) && (gcol0 <= W_ - 4);
    const float* sptr0 = second + (size_t)b * CHW_ + (size_t)grow0 * W_ + gcol0;

    const int k1 = 128 + t;
    const bool act1 = (k1 < NCHUNK);          // t < 52
    const int r1 = k1 / 18, cc1 = k1 % 18;
    const int grow1 = y0 + dy0 + r1;
    const int gcol1 = x0 - 4 + 4 * cc1;
    const bool v1 = act1 && (grow1 >= 0) && (grow1 < H_) && (gcol1 >= 0) && (gcol1 <= W_ - 4);
    const float* sptr1 = second + (size_t)b * CHW_ + (size_t)grow1 * W_ + gcol1;

    const float4 z4 = make_float4(0.f, 0.f, 0.f, 0.f);

    float4 Sa[2], Sb[2], F[2];

    auto loadS = [&](int cc, float4& A, float4& Bv) {
        A = v0 ? *(const float4*)(sptr0 + (size_t)cc * HW_) : z4;
        if (act1) Bv = v1 ? *(const float4*)(sptr1 + (size_t)cc * HW_) : z4;
    };
    auto writeS = [&](int pb, const float4& A, const float4& Bv) {
        *(float4*)&sS[pb][4 * t] = A;
        if (act1) *(float4*)&sS[pb][512 + 4 * t] = Bv;
    };

    // prologue: c0 -> LDS[0]; c1 staged in regs slot 1
    loadS(0, Sa[0], Sb[0]);
    F[0] = *(const float4*)(fptr);
    writeS(0, Sa[0], Sb[0]);
    loadS(1, Sa[1], Sb[1]);
    F[1] = *(const float4*)(fptr + HW_);

    float4 acc[27];
    #pragma unroll
    for (int i = 0; i < 27; ++i) acc[i] = z4;

    #pragma unroll 2
    for (int c = 0; c < C_; ++c) {
        const int pb = c & 1;
        __syncthreads();                       // LDS[pb] (channel c) ready
        if (c + 1 < C_) writeS(pb ^ 1, Sa[pb ^ 1], Sb[pb ^ 1]);   // stage c+1
        const float4 fcur = F[pb];
        if (c + 2 < C_) {                      // prefetch c+2 into freed slot
            loadS(c + 2, Sa[pb], Sb[pb]);
            F[pb] = *(const float4*)(fptr + (size_t)(c + 2) * HW_);
        }

        #pragma unroll
        for (int j = 0; j < 3; ++j) {
            const float* srow = &sS[pb][(ty + j) * SCOLS + 4 * tx];
            float w[12];
            *(float4*)(w + 0) = *(const float4*)(srow);
            *(float4*)(w + 4) = *(const float4*)(srow + 4);
            *(float4*)(w + 8) = *(const float4*)(srow + 8);
            #pragma unroll
            for (int dxi = 0; dxi < 9; ++dxi) {
                float4& a = acc[j * 9 + dxi];
                a.x += fcur.x * w[dxi + 0];
                a.y += fcur.y * w[dxi + 1];
                a.z += fcur.z * w[dxi + 2];
                a.w += fcur.w * w[dxi + 3];
            }
        }
    }

    // epilogue: out[b, d, y, x], d = (3g+j)*9 + dxi
    const float scale = 1.0f / (float)C_;
    #pragma unroll
    for (int j = 0; j < 3; ++j) {
        #pragma unroll
        for (int dxi = 0; dxi < 9; ++dxi) {
            const int d = (3 * g + j) * 9 + dxi;
            float4 r = acc[j * 9 + dxi];
            r.x *= scale; r.y *= scale; r.z *= scale; r.w *= scale;
            *(float4*)(out + ((size_t)b * 81 + d) * HW_ + (size_t)y * W_ + X) = r;
        }
    }
}

extern "C" void kernel_launch(void* const* d_in, const int* in_sizes, int n_in,
                              void* d_out, int out_size, void* d_ws, size_t ws_size,
                              hipStream_t stream) {
    const float* first  = (const float*)d_in[0];
    const float* second = (const float*)d_in[1];
    float* out = (float*)d_out;

    dim3 grid(W_ / TX, H_ / TY, B_ * 3);   // 3 x 16 x 12 = 576 blocks
    dim3 block(128);
    corr_kernel<<<grid, block, 0, stream>>>(first, second, out);
}